// Round 1
// baseline (736.489 us; speedup 1.0000x reference)
//
#include <hip/hip_runtime.h>
#include <hip/hip_bf16.h>

#define V 10000
#define C 1024
#define S 128
#define H 256
#define B 16
#define T 128

typedef unsigned short u16;
typedef unsigned int u32;

static __device__ __forceinline__ float bf2f(u16 x){ return __uint_as_float(((u32)x)<<16); }
static __device__ __forceinline__ u16 f2bf(float f){ u32 u=__float_as_uint(f); return (u16)((u + 0x7FFFu + ((u>>16)&1u))>>16); }
static __device__ __forceinline__ u32 fenc(float f){ u32 b=__float_as_uint(f); return (b&0x80000000u)? ~b : (b|0x80000000u); }
static __device__ __forceinline__ float fdec(u32 e){ u32 b=(e&0x80000000u)? (e&0x7FFFFFFFu) : ~e; return __uint_as_float(b); }

// ---------------- zero accumulators ----------------
__global__ void k_zero(float* __restrict__ sumexp, u32* __restrict__ wb, float* __restrict__ res){
  int i = threadIdx.x + blockIdx.x*blockDim.x;
  if (i < C) sumexp[i] = 0.f;
  if (i < 2) wb[i] = 0u;
  if (i < B) res[i] = 0.f;
}

// ---------------- MLP: h2 = relu(relu(x@w1+b1)@w2+b2+x) ----------------
#define RPB 8
__global__ __launch_bounds__(256) void k_mlp(
    const float* __restrict__ x, const float* __restrict__ w1, const float* __restrict__ b1,
    const float* __restrict__ w2, const float* __restrict__ b2,
    float* __restrict__ out_f32, u16* __restrict__ out_bf16, float* __restrict__ rn2){
  __shared__ float xr[RPB][H];
  __shared__ float h1r[RPB][H];
  const int j = threadIdx.x;
  const int r0 = blockIdx.x * RPB;
  #pragma unroll
  for (int r=0;r<RPB;r++) xr[r][j] = x[(size_t)(r0+r)*H + j];
  __syncthreads();
  float acc[RPB];
  {
    float bj = b1[j];
    #pragma unroll
    for (int r=0;r<RPB;r++) acc[r]=bj;
    for (int k=0;k<H;k++){
      float w = w1[(size_t)k*H + j];
      #pragma unroll
      for (int r=0;r<RPB;r++) acc[r] = fmaf(xr[r][k], w, acc[r]);
    }
  }
  #pragma unroll
  for (int r=0;r<RPB;r++) h1r[r][j] = fmaxf(acc[r], 0.f);
  __syncthreads();
  {
    float bj = b2[j];
    #pragma unroll
    for (int r=0;r<RPB;r++) acc[r] = bj + xr[r][j];
    for (int k=0;k<H;k++){
      float w = w2[(size_t)k*H + j];
      #pragma unroll
      for (int r=0;r<RPB;r++) acc[r] = fmaf(h1r[r][k], w, acc[r]);
    }
  }
  #pragma unroll
  for (int r=0;r<RPB;r++){
    float h2 = fmaxf(acc[r], 0.f);
    if (out_f32)  out_f32 [(size_t)(r0+r)*H + j] = h2;
    if (out_bf16) out_bf16[(size_t)(r0+r)*H + j] = f2bf(h2);
    acc[r] = h2*h2;
  }
  if (rn2){
    __syncthreads();
    #pragma unroll
    for (int r=0;r<RPB;r++) xr[r][j] = acc[r];
    __syncthreads();
    for (int off=128; off>=1; off>>=1){
      if (j < off){
        #pragma unroll
        for (int r=0;r<RPB;r++) xr[r][j] += xr[r][j+off];
      }
      __syncthreads();
    }
    if (j==0){
      #pragma unroll
      for (int r=0;r<RPB;r++) rn2[r0+r] = xr[r][0];
    }
  }
}

// ---------------- start head + log_softmax over C ----------------
__global__ __launch_bounds__(1024) void k_start(
    const float* __restrict__ h2, const float* __restrict__ wo, const float* __restrict__ bo,
    float* __restrict__ start_lp){
  const int c = threadIdx.x;
  const int lane = c & 63, wid = c >> 6;
  __shared__ float red[16];
  __shared__ float Ms, Zs;
  float acc = bo[0];
  const float* row = h2 + (size_t)c*H;
  for (int k=0;k<H;k+=4){
    float4 hv = *(const float4*)(row+k);
    float4 wv = *(const float4*)(wo+k);
    acc = fmaf(hv.x,wv.x,acc); acc = fmaf(hv.y,wv.y,acc);
    acc = fmaf(hv.z,wv.z,acc); acc = fmaf(hv.w,wv.w,acc);
  }
  float m = acc;
  for (int o=1;o<64;o<<=1) m = fmaxf(m, __shfl_xor(m,o));
  if (lane==0) red[wid]=m;
  __syncthreads();
  if (c==0){ float t=red[0]; for(int i=1;i<16;i++) t=fmaxf(t,red[i]); Ms=t; }
  __syncthreads();
  float M = Ms;
  float e = expf(acc - M);
  float sum = e;
  for (int o=1;o<64;o<<=1) sum += __shfl_xor(sum,o);
  __syncthreads();
  if (lane==0) red[wid]=sum;
  __syncthreads();
  if (c==0){ float t=0.f; for(int i=0;i<16;i++) t+=red[i]; Zs=t; }
  __syncthreads();
  start_lp[c] = acc - (M + logf(Zs));
}

// ---------------- transition head + row softmax -> P (bf16 probs) ----------------
#define RC 8
__global__ __launch_bounds__(256) void k_trans(
    const float* __restrict__ h2, const float* __restrict__ wo, const float* __restrict__ bo,
    u16* __restrict__ P){
  __shared__ float xr[RC][H];
  __shared__ float red[4];
  __shared__ float Ms, Zs;
  const int j = threadIdx.x, lane = j&63, wid = j>>6;
  const int r0 = blockIdx.x*RC;
  #pragma unroll
  for (int r=0;r<RC;r++) xr[r][j] = h2[(size_t)(r0+r)*H + j];
  __syncthreads();
  float acc[4][RC];
  #pragma unroll
  for (int m=0;m<4;m++){
    float bv = bo[j + 256*m];
    #pragma unroll
    for (int r=0;r<RC;r++) acc[m][r]=bv;
  }
  for (int k=0;k<H;k++){
    float w0 = wo[(size_t)k*C + j];
    float w1v = wo[(size_t)k*C + j + 256];
    float w2v = wo[(size_t)k*C + j + 512];
    float w3v = wo[(size_t)k*C + j + 768];
    #pragma unroll
    for (int r=0;r<RC;r++){
      float xv = xr[r][k];
      acc[0][r]=fmaf(xv,w0 ,acc[0][r]);
      acc[1][r]=fmaf(xv,w1v,acc[1][r]);
      acc[2][r]=fmaf(xv,w2v,acc[2][r]);
      acc[3][r]=fmaf(xv,w3v,acc[3][r]);
    }
  }
  for (int r=0;r<RC;r++){
    float mx = fmaxf(fmaxf(acc[0][r],acc[1][r]), fmaxf(acc[2][r],acc[3][r]));
    for (int o=1;o<64;o<<=1) mx = fmaxf(mx, __shfl_xor(mx,o));
    if (lane==0) red[wid]=mx;
    __syncthreads();
    if (j==0) Ms = fmaxf(fmaxf(red[0],red[1]),fmaxf(red[2],red[3]));
    __syncthreads();
    float M = Ms;
    float e0=expf(acc[0][r]-M), e1=expf(acc[1][r]-M), e2=expf(acc[2][r]-M), e3=expf(acc[3][r]-M);
    float sl = e0+e1+e2+e3;
    for (int o=1;o<64;o<<=1) sl += __shfl_xor(sl,o);
    __syncthreads();
    if (lane==0) red[wid]=sl;
    __syncthreads();
    if (j==0) Zs = red[0]+red[1]+red[2]+red[3];
    __syncthreads();
    float inv = 1.f/Zs;
    size_t base = (size_t)(r0+r)*C;
    P[base + j      ] = f2bf(e0*inv);
    P[base + j + 256] = f2bf(e1*inv);
    P[base + j + 512] = f2bf(e2*inv);
    P[base + j + 768] = f2bf(e3*inv);
    __syncthreads();
  }
}

// ---------------- transpose term_wo (H,V) -> wot (V,H) ----------------
__global__ __launch_bounds__(256) void k_transpose(const float* __restrict__ wo, float* __restrict__ wot){
  __shared__ float tile[32][33];
  int v0 = blockIdx.x*32, k0 = blockIdx.y*32;
  int tx = threadIdx.x, ty = threadIdx.y; // 32 x 8
  for (int i=0;i<32;i+=8){
    int k = k0+ty+i, v = v0+tx;
    tile[ty+i][tx] = (v < V) ? wo[(size_t)k*V + v] : 0.f;
  }
  __syncthreads();
  for (int i=0;i<32;i+=8){
    int v = v0+ty+i, k = k0+tx;
    if (v < V) wot[(size_t)v*H + k] = tile[tx][ty+i];
  }
}

// ---------------- max wo_t row norm & max bias ----------------
__global__ __launch_bounds__(256) void k_wnorm(const float* __restrict__ wot, const float* __restrict__ bo,
                                               u32* __restrict__ wmax, u32* __restrict__ bmax){
  const int tid = threadIdx.x, lane = tid&63, wid = tid>>6;
  __shared__ float rn[4]; __shared__ float bb[4];
  int v = blockIdx.x*4 + wid;
  float s = 0.f;
  const float* r = wot + (size_t)v*H;
  for (int k=lane;k<H;k+=64){ float x=r[k]; s = fmaf(x,x,s); }
  for (int o=1;o<64;o<<=1) s += __shfl_xor(s,o);
  if (lane==0) rn[wid] = sqrtf(s);
  int bi = blockIdx.x*256 + tid;
  float bv = (bi < V) ? bo[bi] : -1e30f;
  for (int o=1;o<64;o<<=1) bv = fmaxf(bv, __shfl_xor(bv,o));
  if (lane==0) bb[wid] = bv;
  __syncthreads();
  if (tid==0){
    float nm = fmaxf(fmaxf(rn[0],rn[1]),fmaxf(rn[2],rn[3]));
    float bm = fmaxf(fmaxf(bb[0],bb[1]),fmaxf(bb[2],bb[3]));
    atomicMax(wmax, fenc(nm));
    atomicMax(bmax, fenc(bm));
  }
}

__global__ void k_shift(const float* __restrict__ rn2, const u32* __restrict__ wb, float* __restrict__ shift){
  int c = threadIdx.x + blockIdx.x*blockDim.x;
  if (c < C) shift[c] = sqrtf(rn2[c]) * fdec(wb[0]) + fdec(wb[1]) + 1.0f;
}

// ---------------- LT[v,s] = dot(h2_term[c], wot[v]) + bo[v];  masked LSE accumulation ----------------
__global__ __launch_bounds__(128) void k_lt(
    const int* __restrict__ w2s, const u16* __restrict__ h2b, const float* __restrict__ wot,
    const float* __restrict__ bo, const float* __restrict__ shift,
    float* __restrict__ LT, float* __restrict__ sumexp){
  const int v = blockIdx.x;
  const int s = threadIdx.x;
  __shared__ float wv[H];
  __shared__ u32 bm[C/32];
  if (s < C/32) bm[s] = 0u;
  wv[s]     = wot[(size_t)v*H + s];
  wv[s+128] = wot[(size_t)v*H + s + 128];
  __syncthreads();
  const int c = w2s[(size_t)v*S + s];
  u32 old = atomicOr(&bm[c>>5], 1u<<(c&31));
  const bool first = ((old >> (c&31)) & 1u) == 0u;
  float acc = bo[v];
  const u16* hr = h2b + (size_t)c*H;
  for (int k=0;k<H;k+=8){
    uint4 d = *(const uint4*)(hr + k);
    acc = fmaf(bf2f((u16)(d.x&0xFFFFu)), wv[k+0], acc);
    acc = fmaf(bf2f((u16)(d.x>>16)),     wv[k+1], acc);
    acc = fmaf(bf2f((u16)(d.y&0xFFFFu)), wv[k+2], acc);
    acc = fmaf(bf2f((u16)(d.y>>16)),     wv[k+3], acc);
    acc = fmaf(bf2f((u16)(d.z&0xFFFFu)), wv[k+4], acc);
    acc = fmaf(bf2f((u16)(d.z>>16)),     wv[k+5], acc);
    acc = fmaf(bf2f((u16)(d.w&0xFFFFu)), wv[k+6], acc);
    acc = fmaf(bf2f((u16)(d.w>>16)),     wv[k+7], acc);
  }
  LT[(size_t)v*S + s] = acc;
  if (first) atomicAdd(&sumexp[c], expf(acc - shift[c]));
}

__global__ void k_lse(const float* __restrict__ shift, const float* __restrict__ sumexp, float* __restrict__ lse){
  int c = threadIdx.x + blockIdx.x*blockDim.x;
  if (c < C) lse[c] = shift[c] + logf(sumexp[c]);
}

// ---------------- obs[b,t,s] = LT[text,s] - lse[c] ----------------
__global__ __launch_bounds__(128) void k_obs(
    const int* __restrict__ text, const int* __restrict__ w2s,
    const float* __restrict__ LT, const float* __restrict__ lse,
    float* __restrict__ obs){
  const int bt = blockIdx.x;
  const int s = threadIdx.x;
  const int v = text[bt];
  const int c = w2s[(size_t)v*S + s];
  obs[(size_t)bt*S + s] = LT[(size_t)v*S + s] - lse[c];
}

// ---------------- gather pot[b,t,sn,sp] = P[cp[sp], cn[sn]] (bf16) ----------------
__global__ __launch_bounds__(256) void k_pot(
    const int* __restrict__ text, const int* __restrict__ w2s,
    const u16* __restrict__ P, u16* __restrict__ pot){
  const int t = blockIdx.x;  // 0..T-2
  const int b = blockIdx.y;
  __shared__ int cp[S], cn[S];
  __shared__ u32 tileW[S*65];          // u16 tile [sn][sp], row stride 130 u16 (65 words)
  u16* tile16 = (u16*)tileW;
  const int tid = threadIdx.x;
  if (tid < 128) cp[tid]       = w2s[(size_t)text[b*T + t  ]*S + tid];
  else           cn[tid-128]   = w2s[(size_t)text[b*T + t+1]*S + (tid-128)];
  __syncthreads();
  const int sp_half = tid >> 7;
  const int sn = tid & 127;
  const int cnv = cn[sn];
  for (int it=0; it<64; ++it){
    int sp = it*2 + sp_half;
    tile16[sn*130 + sp] = P[(size_t)cp[sp]*C + cnv];
  }
  __syncthreads();
  u16* dst = pot + ((size_t)b*(T-1) + t)*S*S;
  #pragma unroll
  for (int ii=0; ii<(S*S)/(256*8); ++ii){
    int i0 = (ii*256 + tid)*8;
    int sn2 = i0>>7, sp2 = i0&127;
    const u32* tw = tileW + sn2*65 + (sp2>>1);
    uint4 w4; w4.x = tw[0]; w4.y = tw[1]; w4.z = tw[2]; w4.w = tw[3];
    *(uint4*)(dst + i0) = w4;
  }
}

// ---------------- sequential forward scan (scaled-linear space) ----------------
__global__ __launch_bounds__(1024) void k_scan(
    const int* __restrict__ text, const int* __restrict__ w2s,
    const float* __restrict__ start_lp, const float* __restrict__ obs,
    const u16* __restrict__ pot, float* __restrict__ res){
  const int b = blockIdx.x;
  const int tid = threadIdx.x, lane = tid&63, wid = tid>>6;
  __shared__ float a[S], an[S], red[16];
  __shared__ float Msh;
  if (tid < S){
    int c = w2s[(size_t)text[b*T]*S + tid];
    an[tid] = start_lp[c] + obs[(size_t)(b*T)*S + tid];
  }
  __syncthreads();
  float M;
  if (tid < S){
    float m = an[tid];
    for (int o=1;o<64;o<<=1) m = fmaxf(m, __shfl_xor(m,o));
    if (lane==0) red[wid]=m;
  }
  __syncthreads();
  if (tid==0) Msh = fmaxf(red[0], red[1]);
  __syncthreads();
  M = Msh;
  if (tid < S) a[tid] = expf(an[tid] - M);
  __syncthreads();

  const int sn = tid>>3, q = tid&7;
  const u16* pb = pot + (size_t)b*(T-1)*S*S + sn*S + q*16;
  uint4 d0 = *(const uint4*)(pb);
  uint4 d1 = *(const uint4*)(pb + 8);
  for (int t=0; t<T-1; ++t){
    uint4 n0, n1;
    if (t+1 < T-1){
      const u16* pn = pb + (size_t)(t+1)*S*S;
      n0 = *(const uint4*)(pn);
      n1 = *(const uint4*)(pn + 8);
    } else { n0 = d0; n1 = d1; }
    const float* ap = a + q*16;
    float acc = 0.f;
    acc = fmaf(bf2f((u16)(d0.x&0xFFFFu)), ap[0], acc);
    acc = fmaf(bf2f((u16)(d0.x>>16)),     ap[1], acc);
    acc = fmaf(bf2f((u16)(d0.y&0xFFFFu)), ap[2], acc);
    acc = fmaf(bf2f((u16)(d0.y>>16)),     ap[3], acc);
    acc = fmaf(bf2f((u16)(d0.z&0xFFFFu)), ap[4], acc);
    acc = fmaf(bf2f((u16)(d0.z>>16)),     ap[5], acc);
    acc = fmaf(bf2f((u16)(d0.w&0xFFFFu)), ap[6], acc);
    acc = fmaf(bf2f((u16)(d0.w>>16)),     ap[7], acc);
    acc = fmaf(bf2f((u16)(d1.x&0xFFFFu)), ap[8], acc);
    acc = fmaf(bf2f((u16)(d1.x>>16)),     ap[9], acc);
    acc = fmaf(bf2f((u16)(d1.y&0xFFFFu)), ap[10], acc);
    acc = fmaf(bf2f((u16)(d1.y>>16)),     ap[11], acc);
    acc = fmaf(bf2f((u16)(d1.z&0xFFFFu)), ap[12], acc);
    acc = fmaf(bf2f((u16)(d1.z>>16)),     ap[13], acc);
    acc = fmaf(bf2f((u16)(d1.w&0xFFFFu)), ap[14], acc);
    acc = fmaf(bf2f((u16)(d1.w>>16)),     ap[15], acc);
    acc += __shfl_xor(acc,1); acc += __shfl_xor(acc,2); acc += __shfl_xor(acc,4);
    if (q==0) an[sn] = logf(acc) + M + obs[(size_t)(b*T + t + 1)*S + sn];
    __syncthreads();
    if (tid < S){
      float m2 = an[tid];
      for (int o=1;o<64;o<<=1) m2 = fmaxf(m2, __shfl_xor(m2,o));
      if (lane==0) red[wid]=m2;
    }
    __syncthreads();
    if (tid==0) Msh = fmaxf(red[0], red[1]);
    __syncthreads();
    M = Msh;
    if (tid < S) a[tid] = expf(an[tid] - M);
    d0 = n0; d1 = n1;
    __syncthreads();
  }
  float sv = 0.f;
  if (tid < S){
    sv = a[tid];
    for (int o=1;o<64;o<<=1) sv += __shfl_xor(sv,o);
    if (lane==0) red[wid]=sv;
  }
  __syncthreads();
  if (tid==0) res[b] = M + logf(red[0] + red[1]);
}

__global__ void k_final(const float* __restrict__ res, float* __restrict__ out){
  if (threadIdx.x==0){
    float s = 0.f;
    for (int i=0;i<B;i++) s += res[i];
    out[0] = s;
  }
}

extern "C" void kernel_launch(void* const* d_in, const int* in_sizes, int n_in,
                              void* d_out, int out_size, void* d_ws, size_t ws_size,
                              hipStream_t stream){
  const int*   text      = (const int*)d_in[0];
  const int*   w2s       = (const int*)d_in[1];
  const float* start_emb = (const float*)d_in[2];
  const float* start_w1  = (const float*)d_in[3];
  const float* start_b1  = (const float*)d_in[4];
  const float* start_w2  = (const float*)d_in[5];
  const float* start_b2  = (const float*)d_in[6];
  const float* start_wo  = (const float*)d_in[7];
  const float* start_bo  = (const float*)d_in[8];
  const float* state_emb = (const float*)d_in[9];
  const float* trans_w1  = (const float*)d_in[10];
  const float* trans_b1  = (const float*)d_in[11];
  const float* trans_w2  = (const float*)d_in[12];
  const float* trans_b2  = (const float*)d_in[13];
  const float* trans_wo  = (const float*)d_in[14];
  const float* trans_bo  = (const float*)d_in[15];
  const float* pre_emb   = (const float*)d_in[16];
  const float* term_w1   = (const float*)d_in[17];
  const float* term_b1   = (const float*)d_in[18];
  const float* term_w2   = (const float*)d_in[19];
  const float* term_b2   = (const float*)d_in[20];
  const float* term_wo   = (const float*)d_in[21];
  const float* term_bo   = (const float*)d_in[22];

  char* ws = (char*)d_ws;
  size_t off = 0;
  auto alloc = [&](size_t bytes)->char*{ char* p = ws + off; off += (bytes + 255) & ~(size_t)255; return p; };
  float* h2_start = (float*)alloc(sizeof(float)*(size_t)C*H);
  float* h2_trans = (float*)alloc(sizeof(float)*(size_t)C*H);
  u16*   h2_term  = (u16*)  alloc(sizeof(u16)*(size_t)C*H);
  float* rn2      = (float*)alloc(sizeof(float)*C);
  float* start_lp = (float*)alloc(sizeof(float)*C);
  float* shift    = (float*)alloc(sizeof(float)*C);
  float* sumexp   = (float*)alloc(sizeof(float)*C);
  float* lse      = (float*)alloc(sizeof(float)*C);
  u32*   wb       = (u32*)  alloc(sizeof(u32)*2);
  float* resb     = (float*)alloc(sizeof(float)*B);
  u16*   P        = (u16*)  alloc(sizeof(u16)*(size_t)C*C);
  float* wot      = (float*)alloc(sizeof(float)*(size_t)V*H);
  float* LT       = (float*)alloc(sizeof(float)*(size_t)V*S);
  float* obs      = (float*)alloc(sizeof(float)*(size_t)B*T*S);
  u16*   pot      = (u16*)  alloc(sizeof(u16)*(size_t)B*(T-1)*S*S);
  (void)ws_size; (void)in_sizes; (void)n_in; (void)out_size;

  k_zero<<<dim3((C+255)/256), dim3(256), 0, stream>>>(sumexp, wb, resb);
  k_mlp<<<dim3(C/RPB), dim3(256), 0, stream>>>(start_emb, start_w1, start_b1, start_w2, start_b2, h2_start, (u16*)nullptr, (float*)nullptr);
  k_mlp<<<dim3(C/RPB), dim3(256), 0, stream>>>(state_emb, trans_w1, trans_b1, trans_w2, trans_b2, h2_trans, (u16*)nullptr, (float*)nullptr);
  k_mlp<<<dim3(C/RPB), dim3(256), 0, stream>>>(pre_emb, term_w1, term_b1, term_w2, term_b2, (float*)nullptr, h2_term, rn2);
  k_start<<<dim3(1), dim3(1024), 0, stream>>>(h2_start, start_wo, start_bo, start_lp);
  k_trans<<<dim3(C/RC), dim3(256), 0, stream>>>(h2_trans, trans_wo, trans_bo, P);
  k_transpose<<<dim3((V+31)/32, H/32), dim3(32,8), 0, stream>>>(term_wo, wot);
  k_wnorm<<<dim3(V/4), dim3(256), 0, stream>>>(wot, term_bo, wb, wb+1);
  k_shift<<<dim3((C+255)/256), dim3(256), 0, stream>>>(rn2, wb, shift);
  k_lt<<<dim3(V), dim3(128), 0, stream>>>(w2s, h2_term, wot, term_bo, shift, LT, sumexp);
  k_lse<<<dim3((C+255)/256), dim3(256), 0, stream>>>(shift, sumexp, lse);
  k_obs<<<dim3(B*T), dim3(128), 0, stream>>>(text, w2s, LT, lse, obs);
  k_pot<<<dim3(T-1, B), dim3(256), 0, stream>>>(text, w2s, P, pot);
  k_scan<<<dim3(B), dim3(1024), 0, stream>>>(text, w2s, start_lp, obs, pot, resb);
  k_final<<<dim3(1), dim3(64), 0, stream>>>(resb, (float*)d_out);
}

// Round 2
// 492.254 us; speedup vs baseline: 1.4962x; 1.4962x over previous
//
#include <hip/hip_runtime.h>
#include <hip/hip_bf16.h>

#define V 10000
#define VP 10112
#define C 1024
#define S 128
#define H 256
#define B 16
#define T 128
#define NR 32      // sumexp replicas
#define LDK 40     // padded LDS row length (u16) for k_em

typedef unsigned short u16;
typedef unsigned int u32;
typedef __bf16 bf16x8 __attribute__((ext_vector_type(8)));
typedef float f32x4 __attribute__((ext_vector_type(4)));

static __device__ __forceinline__ float bf2f(u16 x){ return __uint_as_float(((u32)x)<<16); }
static __device__ __forceinline__ u16 f2bf(float f){ u32 u=__float_as_uint(f); return (u16)((u + 0x7FFFu + ((u>>16)&1u))>>16); }
static __device__ __forceinline__ u32 fenc(float f){ u32 b=__float_as_uint(f); return (b&0x80000000u)? ~b : (b|0x80000000u); }
static __device__ __forceinline__ float fdec(u32 e){ u32 b=(e&0x80000000u)? (e&0x7FFFFFFFu) : ~e; return __uint_as_float(b); }

// ---------------- zero accumulators ----------------
__global__ void k_zero(float* __restrict__ sumexp, u32* __restrict__ wb, float* __restrict__ res){
  int i = threadIdx.x + blockIdx.x*blockDim.x;
  if (i < C*NR) sumexp[i] = 0.f;
  if (i < 2) wb[i] = 0u;
  if (i < B) res[i] = 0.f;
}

// ---------------- MLP: h2 = relu(relu(x@w1+b1)@w2+b2+x) ----------------
#define RPB 8
__global__ __launch_bounds__(256) void k_mlp(
    const float* __restrict__ x, const float* __restrict__ w1, const float* __restrict__ b1,
    const float* __restrict__ w2, const float* __restrict__ b2,
    float* __restrict__ out_f32, u16* __restrict__ out_bf16, float* __restrict__ rn2){
  __shared__ float xr[RPB][H];
  __shared__ float h1r[RPB][H];
  const int j = threadIdx.x;
  const int r0 = blockIdx.x * RPB;
  #pragma unroll
  for (int r=0;r<RPB;r++) xr[r][j] = x[(size_t)(r0+r)*H + j];
  __syncthreads();
  float acc[RPB];
  {
    float bj = b1[j];
    #pragma unroll
    for (int r=0;r<RPB;r++) acc[r]=bj;
    for (int k=0;k<H;k++){
      float w = w1[(size_t)k*H + j];
      #pragma unroll
      for (int r=0;r<RPB;r++) acc[r] = fmaf(xr[r][k], w, acc[r]);
    }
  }
  #pragma unroll
  for (int r=0;r<RPB;r++) h1r[r][j] = fmaxf(acc[r], 0.f);
  __syncthreads();
  {
    float bj = b2[j];
    #pragma unroll
    for (int r=0;r<RPB;r++) acc[r] = bj + xr[r][j];
    for (int k=0;k<H;k++){
      float w = w2[(size_t)k*H + j];
      #pragma unroll
      for (int r=0;r<RPB;r++) acc[r] = fmaf(h1r[r][k], w, acc[r]);
    }
  }
  #pragma unroll
  for (int r=0;r<RPB;r++){
    float h2 = fmaxf(acc[r], 0.f);
    if (out_f32)  out_f32 [(size_t)(r0+r)*H + j] = h2;
    if (out_bf16) out_bf16[(size_t)(r0+r)*H + j] = f2bf(h2);
    acc[r] = h2*h2;
  }
  if (rn2){
    __syncthreads();
    #pragma unroll
    for (int r=0;r<RPB;r++) xr[r][j] = acc[r];
    __syncthreads();
    for (int off=128; off>=1; off>>=1){
      if (j < off){
        #pragma unroll
        for (int r=0;r<RPB;r++) xr[r][j] += xr[r][j+off];
      }
      __syncthreads();
    }
    if (j==0){
      #pragma unroll
      for (int r=0;r<RPB;r++) rn2[r0+r] = xr[r][0];
    }
  }
}

// ---------------- start head + log_softmax over C ----------------
__global__ __launch_bounds__(1024) void k_start(
    const float* __restrict__ h2, const float* __restrict__ wo, const float* __restrict__ bo,
    float* __restrict__ start_lp){
  const int c = threadIdx.x;
  const int lane = c & 63, wid = c >> 6;
  __shared__ float red[16];
  __shared__ float Ms, Zs;
  float acc = bo[0];
  const float* row = h2 + (size_t)c*H;
  for (int k=0;k<H;k+=4){
    float4 hv = *(const float4*)(row+k);
    float4 wv = *(const float4*)(wo+k);
    acc = fmaf(hv.x,wv.x,acc); acc = fmaf(hv.y,wv.y,acc);
    acc = fmaf(hv.z,wv.z,acc); acc = fmaf(hv.w,wv.w,acc);
  }
  float m = acc;
  for (int o=1;o<64;o<<=1) m = fmaxf(m, __shfl_xor(m,o));
  if (lane==0) red[wid]=m;
  __syncthreads();
  if (c==0){ float t=red[0]; for(int i=1;i<16;i++) t=fmaxf(t,red[i]); Ms=t; }
  __syncthreads();
  float M = Ms;
  float e = expf(acc - M);
  float sum = e;
  for (int o=1;o<64;o<<=1) sum += __shfl_xor(sum,o);
  __syncthreads();
  if (lane==0) red[wid]=sum;
  __syncthreads();
  if (c==0){ float t=0.f; for(int i=0;i<16;i++) t+=red[i]; Zs=t; }
  __syncthreads();
  start_lp[c] = acc - (M + logf(Zs));
}

// ---------------- transition head + row softmax -> P (bf16 probs) ----------------
#define RC 8
__global__ __launch_bounds__(256) void k_trans(
    const float* __restrict__ h2, const float* __restrict__ wo, const float* __restrict__ bo,
    u16* __restrict__ P){
  __shared__ float xr[RC][H];
  __shared__ float red[4];
  __shared__ float Ms, Zs;
  const int j = threadIdx.x, lane = j&63, wid = j>>6;
  const int r0 = blockIdx.x*RC;
  #pragma unroll
  for (int r=0;r<RC;r++) xr[r][j] = h2[(size_t)(r0+r)*H + j];
  __syncthreads();
  float acc[4][RC];
  #pragma unroll
  for (int m=0;m<4;m++){
    float bv = bo[j + 256*m];
    #pragma unroll
    for (int r=0;r<RC;r++) acc[m][r]=bv;
  }
  for (int k=0;k<H;k++){
    float w0 = wo[(size_t)k*C + j];
    float w1v = wo[(size_t)k*C + j + 256];
    float w2v = wo[(size_t)k*C + j + 512];
    float w3v = wo[(size_t)k*C + j + 768];
    #pragma unroll
    for (int r=0;r<RC;r++){
      float xv = xr[r][k];
      acc[0][r]=fmaf(xv,w0 ,acc[0][r]);
      acc[1][r]=fmaf(xv,w1v,acc[1][r]);
      acc[2][r]=fmaf(xv,w2v,acc[2][r]);
      acc[3][r]=fmaf(xv,w3v,acc[3][r]);
    }
  }
  for (int r=0;r<RC;r++){
    float mx = fmaxf(fmaxf(acc[0][r],acc[1][r]), fmaxf(acc[2][r],acc[3][r]));
    for (int o=1;o<64;o<<=1) mx = fmaxf(mx, __shfl_xor(mx,o));
    if (lane==0) red[wid]=mx;
    __syncthreads();
    if (j==0) Ms = fmaxf(fmaxf(red[0],red[1]),fmaxf(red[2],red[3]));
    __syncthreads();
    float M = Ms;
    float e0=expf(acc[0][r]-M), e1=expf(acc[1][r]-M), e2=expf(acc[2][r]-M), e3=expf(acc[3][r]-M);
    float sl = e0+e1+e2+e3;
    for (int o=1;o<64;o<<=1) sl += __shfl_xor(sl,o);
    __syncthreads();
    if (lane==0) red[wid]=sl;
    __syncthreads();
    if (j==0) Zs = red[0]+red[1]+red[2]+red[3];
    __syncthreads();
    float inv = 1.f/Zs;
    size_t base = (size_t)(r0+r)*C;
    P[base + j      ] = f2bf(e0*inv);
    P[base + j + 256] = f2bf(e1*inv);
    P[base + j + 512] = f2bf(e2*inv);
    P[base + j + 768] = f2bf(e3*inv);
    __syncthreads();
  }
}

// ---------------- transpose term_wo (H,V) -> wotb (VP,H) bf16, zero-padded ----------------
__global__ __launch_bounds__(256) void k_transpose(const float* __restrict__ wo, u16* __restrict__ wotb){
  __shared__ float tile[32][33];
  int v0 = blockIdx.x*32, k0 = blockIdx.y*32;
  int tx = threadIdx.x, ty = threadIdx.y; // 32 x 8
  for (int i=0;i<32;i+=8){
    int k = k0+ty+i, v = v0+tx;
    tile[ty+i][tx] = (v < V) ? wo[(size_t)k*V + v] : 0.f;
  }
  __syncthreads();
  for (int i=0;i<32;i+=8){
    int v = v0+ty+i, k = k0+tx;
    wotb[(size_t)v*H + k] = f2bf(tile[tx][ty+i]);
  }
}

// ---------------- max wotb row norm & max bias ----------------
__global__ __launch_bounds__(256) void k_wnorm(const u16* __restrict__ wotb, const float* __restrict__ bo,
                                               u32* __restrict__ wmax, u32* __restrict__ bmax){
  const int tid = threadIdx.x, lane = tid&63, wid = tid>>6;
  __shared__ float rn[4]; __shared__ float bb[4];
  int v = blockIdx.x*4 + wid;
  float s = 0.f;
  const u16* r = wotb + (size_t)v*H;
  for (int k=lane;k<H;k+=64){ float x=bf2f(r[k]); s = fmaf(x,x,s); }
  for (int o=1;o<64;o<<=1) s += __shfl_xor(s,o);
  if (lane==0) rn[wid] = sqrtf(s);
  int bi = blockIdx.x*256 + tid;
  float bv = (bi < V) ? bo[bi] : -1e30f;
  for (int o=1;o<64;o<<=1) bv = fmaxf(bv, __shfl_xor(bv,o));
  if (lane==0) bb[wid] = bv;
  __syncthreads();
  if (tid==0){
    float nm = fmaxf(fmaxf(rn[0],rn[1]),fmaxf(rn[2],rn[3]));
    float bm = fmaxf(fmaxf(bb[0],bb[1]),fmaxf(bb[2],bb[3]));
    atomicMax(wmax, fenc(nm));
    atomicMax(bmax, fenc(bm));
  }
}

__global__ void k_shift(const float* __restrict__ rn2, const u32* __restrict__ wb, float* __restrict__ shift){
  int c = threadIdx.x + blockIdx.x*blockDim.x;
  // 1.005 covers bf16 rounding of h (norms computed pre-rounding); +1.0 slack
  if (c < C) shift[c] = sqrtf(rn2[c]) * 1.005f * fdec(wb[0]) + fdec(wb[1]) + 1.0f;
}

// ---------------- EM = h2_term(C,H) @ wotb(VP,H)^T + bo  (bf16 MFMA, fp32 out) ----------------
__global__ __launch_bounds__(256) void k_em(
    const u16* __restrict__ A, const u16* __restrict__ BT,
    const float* __restrict__ bo, float* __restrict__ EM){
  __shared__ u16 As[128*LDK];
  __shared__ u16 Bs[128*LDK];
  const int tid = threadIdx.x;
  const int lane = tid & 63, wave = tid >> 6;
  const int wm = wave >> 1, wn = wave & 1;
  const int m0 = blockIdx.y * 128, n0 = blockIdx.x * 128;
  const int lr = lane & 15, lg = lane >> 4;
  f32x4 acc[4][4] = {};
  const int sr = tid >> 1, sh = (tid & 1) * 16;
  for (int ks = 0; ks < H; ks += 32){
    const u16* ga = A  + (size_t)(m0 + sr)*H + ks + sh;
    const u16* gb = BT + (size_t)(n0 + sr)*H + ks + sh;
    uint4 a0 = *(const uint4*)ga;
    uint4 a1 = *(const uint4*)(ga + 8);
    uint4 b0 = *(const uint4*)gb;
    uint4 b1 = *(const uint4*)(gb + 8);
    __syncthreads();
    *(uint4*)&As[sr*LDK + sh]     = a0;
    *(uint4*)&As[sr*LDK + sh + 8] = a1;
    *(uint4*)&Bs[sr*LDK + sh]     = b0;
    *(uint4*)&Bs[sr*LDK + sh + 8] = b1;
    __syncthreads();
    bf16x8 af[4], bfr[4];
    #pragma unroll
    for (int m=0;m<4;m++) af[m]  = *(const bf16x8*)&As[(wm*64 + m*16 + lr)*LDK + lg*8];
    #pragma unroll
    for (int n=0;n<4;n++) bfr[n] = *(const bf16x8*)&Bs[(wn*64 + n*16 + lr)*LDK + lg*8];
    #pragma unroll
    for (int m=0;m<4;m++)
      #pragma unroll
      for (int n=0;n<4;n++)
        acc[m][n] = __builtin_amdgcn_mfma_f32_16x16x32_bf16(af[m], bfr[n], acc[m][n], 0,0,0);
  }
  #pragma unroll
  for (int m=0;m<4;m++){
    int r_g = m0 + wm*64 + m*16 + lg*4;
    #pragma unroll
    for (int n=0;n<4;n++){
      int n_g = n0 + wn*64 + n*16 + lr;
      float bv = (n_g < V) ? bo[n_g] : 0.f;
      #pragma unroll
      for (int reg=0; reg<4; reg++){
        EM[(size_t)(r_g + reg)*VP + n_g] = acc[m][n][reg] + bv;
      }
    }
  }
}

// ---------------- gather LT + dedupe + masked LSE partial sums ----------------
__global__ __launch_bounds__(128) void k_gather(
    const int* __restrict__ w2s, const float* __restrict__ EM,
    const float* __restrict__ shift,
    float* __restrict__ LT, float* __restrict__ sumexp){
  const int v = blockIdx.x;
  const int s = threadIdx.x;
  __shared__ u32 bm[C/32];
  if (s < C/32) bm[s] = 0u;
  __syncthreads();
  const int c = w2s[(size_t)v*S + s];
  u32 old = atomicOr(&bm[c>>5], 1u<<(c&31));
  const bool first = ((old >> (c&31)) & 1u) == 0u;
  float val = EM[(size_t)c*VP + v];
  LT[(size_t)v*S + s] = val;
  if (first) atomicAdd(&sumexp[(size_t)(v & (NR-1))*C + c], expf(val - shift[c]));
}

__global__ void k_lse(const float* __restrict__ shift, const float* __restrict__ sumexp, float* __restrict__ lse){
  int c = threadIdx.x + blockIdx.x*blockDim.x;
  if (c < C){
    float s = 0.f;
    for (int r=0;r<NR;r++) s += sumexp[(size_t)r*C + c];
    lse[c] = shift[c] + logf(s);
  }
}

// ---------------- obs[b,t,s] = LT[text,s] - lse[c] ----------------
__global__ __launch_bounds__(128) void k_obs(
    const int* __restrict__ text, const int* __restrict__ w2s,
    const float* __restrict__ LT, const float* __restrict__ lse,
    float* __restrict__ obs){
  const int bt = blockIdx.x;
  const int s = threadIdx.x;
  const int v = text[bt];
  const int c = w2s[(size_t)v*S + s];
  obs[(size_t)bt*S + s] = LT[(size_t)v*S + s] - lse[c];
}

// ---------------- gather pot[b,t,sn,sp] = P[cp[sp], cn[sn]] (bf16) ----------------
__global__ __launch_bounds__(256) void k_pot(
    const int* __restrict__ text, const int* __restrict__ w2s,
    const u16* __restrict__ P, u16* __restrict__ pot){
  const int t = blockIdx.x;  // 0..T-2
  const int b = blockIdx.y;
  __shared__ int cp[S], cn[S];
  __shared__ u32 tileW[S*65];          // u16 tile [sn][sp], row stride 130 u16 (65 words)
  u16* tile16 = (u16*)tileW;
  const int tid = threadIdx.x;
  if (tid < 128) cp[tid]       = w2s[(size_t)text[b*T + t  ]*S + tid];
  else           cn[tid-128]   = w2s[(size_t)text[b*T + t+1]*S + (tid-128)];
  __syncthreads();
  const int sp_half = tid >> 7;
  const int sn = tid & 127;
  const int cnv = cn[sn];
  for (int it=0; it<64; ++it){
    int sp = it*2 + sp_half;
    tile16[sn*130 + sp] = P[(size_t)cp[sp]*C + cnv];
  }
  __syncthreads();
  u16* dst = pot + ((size_t)b*(T-1) + t)*S*S;
  #pragma unroll
  for (int ii=0; ii<(S*S)/(256*8); ++ii){
    int i0 = (ii*256 + tid)*8;
    int sn2 = i0>>7, sp2 = i0&127;
    const u32* tw = tileW + sn2*65 + (sp2>>1);
    uint4 w4; w4.x = tw[0]; w4.y = tw[1]; w4.z = tw[2]; w4.w = tw[3];
    *(uint4*)(dst + i0) = w4;
  }
}

// ---------------- sequential forward scan (scaled-linear space) ----------------
__global__ __launch_bounds__(1024) void k_scan(
    const int* __restrict__ text, const int* __restrict__ w2s,
    const float* __restrict__ start_lp, const float* __restrict__ obs,
    const u16* __restrict__ pot, float* __restrict__ res){
  const int b = blockIdx.x;
  const int tid = threadIdx.x, lane = tid&63, wid = tid>>6;
  __shared__ float a[S], an[S], red[16];
  __shared__ float Msh;
  if (tid < S){
    int c = w2s[(size_t)text[b*T]*S + tid];
    an[tid] = start_lp[c] + obs[(size_t)(b*T)*S + tid];
  }
  __syncthreads();
  float M;
  if (tid < S){
    float m = an[tid];
    for (int o=1;o<64;o<<=1) m = fmaxf(m, __shfl_xor(m,o));
    if (lane==0) red[wid]=m;
  }
  __syncthreads();
  if (tid==0) Msh = fmaxf(red[0], red[1]);
  __syncthreads();
  M = Msh;
  if (tid < S) a[tid] = expf(an[tid] - M);
  __syncthreads();

  const int sn = tid>>3, q = tid&7;
  const u16* pb = pot + (size_t)b*(T-1)*S*S + sn*S + q*16;
  uint4 d0 = *(const uint4*)(pb);
  uint4 d1 = *(const uint4*)(pb + 8);
  for (int t=0; t<T-1; ++t){
    uint4 n0, n1;
    if (t+1 < T-1){
      const u16* pn = pb + (size_t)(t+1)*S*S;
      n0 = *(const uint4*)(pn);
      n1 = *(const uint4*)(pn + 8);
    } else { n0 = d0; n1 = d1; }
    const float* ap = a + q*16;
    float acc = 0.f;
    acc = fmaf(bf2f((u16)(d0.x&0xFFFFu)), ap[0], acc);
    acc = fmaf(bf2f((u16)(d0.x>>16)),     ap[1], acc);
    acc = fmaf(bf2f((u16)(d0.y&0xFFFFu)), ap[2], acc);
    acc = fmaf(bf2f((u16)(d0.y>>16)),     ap[3], acc);
    acc = fmaf(bf2f((u16)(d0.z&0xFFFFu)), ap[4], acc);
    acc = fmaf(bf2f((u16)(d0.z>>16)),     ap[5], acc);
    acc = fmaf(bf2f((u16)(d0.w&0xFFFFu)), ap[6], acc);
    acc = fmaf(bf2f((u16)(d0.w>>16)),     ap[7], acc);
    acc = fmaf(bf2f((u16)(d1.x&0xFFFFu)), ap[8], acc);
    acc = fmaf(bf2f((u16)(d1.x>>16)),     ap[9], acc);
    acc = fmaf(bf2f((u16)(d1.y&0xFFFFu)), ap[10], acc);
    acc = fmaf(bf2f((u16)(d1.y>>16)),     ap[11], acc);
    acc = fmaf(bf2f((u16)(d1.z&0xFFFFu)), ap[12], acc);
    acc = fmaf(bf2f((u16)(d1.z>>16)),     ap[13], acc);
    acc = fmaf(bf2f((u16)(d1.w&0xFFFFu)), ap[14], acc);
    acc = fmaf(bf2f((u16)(d1.w>>16)),     ap[15], acc);
    acc += __shfl_xor(acc,1); acc += __shfl_xor(acc,2); acc += __shfl_xor(acc,4);
    if (q==0) an[sn] = logf(acc) + M + obs[(size_t)(b*T + t + 1)*S + sn];
    __syncthreads();
    if (tid < S){
      float m2 = an[tid];
      for (int o=1;o<64;o<<=1) m2 = fmaxf(m2, __shfl_xor(m2,o));
      if (lane==0) red[wid]=m2;
    }
    __syncthreads();
    if (tid==0) Msh = fmaxf(red[0], red[1]);
    __syncthreads();
    M = Msh;
    if (tid < S) a[tid] = expf(an[tid] - M);
    d0 = n0; d1 = n1;
    __syncthreads();
  }
  float sv = 0.f;
  if (tid < S){
    sv = a[tid];
    for (int o=1;o<64;o<<=1) sv += __shfl_xor(sv,o);
    if (lane==0) red[wid]=sv;
  }
  __syncthreads();
  if (tid==0) res[b] = M + logf(red[0] + red[1]);
}

__global__ void k_final(const float* __restrict__ res, float* __restrict__ out){
  if (threadIdx.x==0){
    float s = 0.f;
    for (int i=0;i<B;i++) s += res[i];
    out[0] = s;
  }
}

extern "C" void kernel_launch(void* const* d_in, const int* in_sizes, int n_in,
                              void* d_out, int out_size, void* d_ws, size_t ws_size,
                              hipStream_t stream){
  const int*   text      = (const int*)d_in[0];
  const int*   w2s       = (const int*)d_in[1];
  const float* start_emb = (const float*)d_in[2];
  const float* start_w1  = (const float*)d_in[3];
  const float* start_b1  = (const float*)d_in[4];
  const float* start_w2  = (const float*)d_in[5];
  const float* start_b2  = (const float*)d_in[6];
  const float* start_wo  = (const float*)d_in[7];
  const float* start_bo  = (const float*)d_in[8];
  const float* state_emb = (const float*)d_in[9];
  const float* trans_w1  = (const float*)d_in[10];
  const float* trans_b1  = (const float*)d_in[11];
  const float* trans_w2  = (const float*)d_in[12];
  const float* trans_b2  = (const float*)d_in[13];
  const float* trans_wo  = (const float*)d_in[14];
  const float* trans_bo  = (const float*)d_in[15];
  const float* pre_emb   = (const float*)d_in[16];
  const float* term_w1   = (const float*)d_in[17];
  const float* term_b1   = (const float*)d_in[18];
  const float* term_w2   = (const float*)d_in[19];
  const float* term_b2   = (const float*)d_in[20];
  const float* term_wo   = (const float*)d_in[21];
  const float* term_bo   = (const float*)d_in[22];

  char* ws = (char*)d_ws;
  size_t off = 0;
  auto alloc = [&](size_t bytes)->char*{ char* p = ws + off; off += (bytes + 255) & ~(size_t)255; return p; };
  float* h2_start = (float*)alloc(sizeof(float)*(size_t)C*H);
  float* h2_trans = (float*)alloc(sizeof(float)*(size_t)C*H);
  u16*   h2_term  = (u16*)  alloc(sizeof(u16)*(size_t)C*H);
  float* rn2      = (float*)alloc(sizeof(float)*C);
  float* start_lp = (float*)alloc(sizeof(float)*C);
  float* shift    = (float*)alloc(sizeof(float)*C);
  float* sumexp   = (float*)alloc(sizeof(float)*(size_t)C*NR);
  float* lse      = (float*)alloc(sizeof(float)*C);
  u32*   wb       = (u32*)  alloc(sizeof(u32)*2);
  float* resb     = (float*)alloc(sizeof(float)*B);
  u16*   P        = (u16*)  alloc(sizeof(u16)*(size_t)C*C);
  u16*   wotb     = (u16*)  alloc(sizeof(u16)*(size_t)VP*H);
  float* LT       = (float*)alloc(sizeof(float)*(size_t)V*S);
  float* obs      = (float*)alloc(sizeof(float)*(size_t)B*T*S);
  u16*   pot      = (u16*)  alloc(sizeof(u16)*(size_t)B*(T-1)*S*S);  // >= EM bytes
  float* EM       = (float*)pot;   // aliased: EM dead before k_pot writes pot
  (void)ws_size; (void)in_sizes; (void)n_in; (void)out_size;

  k_zero<<<dim3((C*NR+255)/256), dim3(256), 0, stream>>>(sumexp, wb, resb);
  k_mlp<<<dim3(C/RPB), dim3(256), 0, stream>>>(start_emb, start_w1, start_b1, start_w2, start_b2, h2_start, (u16*)nullptr, (float*)nullptr);
  k_mlp<<<dim3(C/RPB), dim3(256), 0, stream>>>(state_emb, trans_w1, trans_b1, trans_w2, trans_b2, h2_trans, (u16*)nullptr, (float*)nullptr);
  k_mlp<<<dim3(C/RPB), dim3(256), 0, stream>>>(pre_emb, term_w1, term_b1, term_w2, term_b2, (float*)nullptr, h2_term, rn2);
  k_start<<<dim3(1), dim3(1024), 0, stream>>>(h2_start, start_wo, start_bo, start_lp);
  k_trans<<<dim3(C/RC), dim3(256), 0, stream>>>(h2_trans, trans_wo, trans_bo, P);
  k_transpose<<<dim3(VP/32, H/32), dim3(32,8), 0, stream>>>(term_wo, wotb);
  k_wnorm<<<dim3(VP/4), dim3(256), 0, stream>>>(wotb, term_bo, wb, wb+1);
  k_shift<<<dim3((C+255)/256), dim3(256), 0, stream>>>(rn2, wb, shift);
  k_em<<<dim3(VP/128, C/128), dim3(256), 0, stream>>>(h2_term, wotb, term_bo, EM);
  k_gather<<<dim3(V), dim3(128), 0, stream>>>(w2s, EM, shift, LT, sumexp);
  k_lse<<<dim3((C+255)/256), dim3(256), 0, stream>>>(shift, sumexp, lse);
  k_obs<<<dim3(B*T), dim3(128), 0, stream>>>(text, w2s, LT, lse, obs);
  k_pot<<<dim3(T-1, B), dim3(256), 0, stream>>>(text, w2s, P, pot);
  k_scan<<<dim3(B), dim3(1024), 0, stream>>>(text, w2s, start_lp, obs, pot, resb);
  k_final<<<dim3(1), dim3(64), 0, stream>>>(resb, (float*)d_out);
}

// Round 3
// 419.492 us; speedup vs baseline: 1.7557x; 1.1735x over previous
//
#include <hip/hip_runtime.h>
#include <hip/hip_bf16.h>

#define V 10000
#define VP 10112
#define C 1024
#define S 128
#define H 256
#define B 16
#define T 128
#define NR 32      // sumexp replicas
#define LDK 40     // padded LDS row length (u16) for k_em

typedef unsigned short u16;
typedef unsigned int u32;
typedef __bf16 bf16x8 __attribute__((ext_vector_type(8)));
typedef float f32x4 __attribute__((ext_vector_type(4)));

static __device__ __forceinline__ float bf2f(u16 x){ return __uint_as_float(((u32)x)<<16); }
static __device__ __forceinline__ u16 f2bf(float f){ u32 u=__float_as_uint(f); return (u16)((u + 0x7FFFu + ((u>>16)&1u))>>16); }
static __device__ __forceinline__ u32 fenc(float f){ u32 b=__float_as_uint(f); return (b&0x80000000u)? ~b : (b|0x80000000u); }
static __device__ __forceinline__ float fdec(u32 e){ u32 b=(e&0x80000000u)? (e&0x7FFFFFFFu) : ~e; return __uint_as_float(b); }

// ---------------- zero accumulators ----------------
__global__ void k_zero(float* __restrict__ sumexp, u32* __restrict__ wb, float* __restrict__ res){
  int i = threadIdx.x + blockIdx.x*blockDim.x;
  if (i < C*NR) sumexp[i] = 0.f;
  if (i < 2) wb[i] = 0u;
  if (i < B) res[i] = 0.f;
}

// ---------------- MLP: h2 = relu(relu(x@w1+b1)@w2+b2+x) ----------------
#define RPB 8
__global__ __launch_bounds__(256) void k_mlp(
    const float* __restrict__ x, const float* __restrict__ w1, const float* __restrict__ b1,
    const float* __restrict__ w2, const float* __restrict__ b2,
    float* __restrict__ out_f32, u16* __restrict__ out_bf16, float* __restrict__ rn2){
  __shared__ float xr[RPB][H];
  __shared__ float h1r[RPB][H];
  const int j = threadIdx.x;
  const int r0 = blockIdx.x * RPB;
  #pragma unroll
  for (int r=0;r<RPB;r++) xr[r][j] = x[(size_t)(r0+r)*H + j];
  __syncthreads();
  float acc[RPB];
  {
    float bj = b1[j];
    #pragma unroll
    for (int r=0;r<RPB;r++) acc[r]=bj;
    for (int k=0;k<H;k++){
      float w = w1[(size_t)k*H + j];
      #pragma unroll
      for (int r=0;r<RPB;r++) acc[r] = fmaf(xr[r][k], w, acc[r]);
    }
  }
  #pragma unroll
  for (int r=0;r<RPB;r++) h1r[r][j] = fmaxf(acc[r], 0.f);
  __syncthreads();
  {
    float bj = b2[j];
    #pragma unroll
    for (int r=0;r<RPB;r++) acc[r] = bj + xr[r][j];
    for (int k=0;k<H;k++){
      float w = w2[(size_t)k*H + j];
      #pragma unroll
      for (int r=0;r<RPB;r++) acc[r] = fmaf(h1r[r][k], w, acc[r]);
    }
  }
  #pragma unroll
  for (int r=0;r<RPB;r++){
    float h2 = fmaxf(acc[r], 0.f);
    if (out_f32)  out_f32 [(size_t)(r0+r)*H + j] = h2;
    if (out_bf16) out_bf16[(size_t)(r0+r)*H + j] = f2bf(h2);
    acc[r] = h2*h2;
  }
  if (rn2){
    __syncthreads();
    #pragma unroll
    for (int r=0;r<RPB;r++) xr[r][j] = acc[r];
    __syncthreads();
    for (int off=128; off>=1; off>>=1){
      if (j < off){
        #pragma unroll
        for (int r=0;r<RPB;r++) xr[r][j] += xr[r][j+off];
      }
      __syncthreads();
    }
    if (j==0){
      #pragma unroll
      for (int r=0;r<RPB;r++) rn2[r0+r] = xr[r][0];
    }
  }
}

// ---------------- start head + log_softmax over C ----------------
__global__ __launch_bounds__(1024) void k_start(
    const float* __restrict__ h2, const float* __restrict__ wo, const float* __restrict__ bo,
    float* __restrict__ start_lp){
  const int c = threadIdx.x;
  const int lane = c & 63, wid = c >> 6;
  __shared__ float red[16];
  __shared__ float Ms, Zs;
  float acc = bo[0];
  const float* row = h2 + (size_t)c*H;
  for (int k=0;k<H;k+=4){
    float4 hv = *(const float4*)(row+k);
    float4 wv = *(const float4*)(wo+k);
    acc = fmaf(hv.x,wv.x,acc); acc = fmaf(hv.y,wv.y,acc);
    acc = fmaf(hv.z,wv.z,acc); acc = fmaf(hv.w,wv.w,acc);
  }
  float m = acc;
  for (int o=1;o<64;o<<=1) m = fmaxf(m, __shfl_xor(m,o));
  if (lane==0) red[wid]=m;
  __syncthreads();
  if (c==0){ float t=red[0]; for(int i=1;i<16;i++) t=fmaxf(t,red[i]); Ms=t; }
  __syncthreads();
  float M = Ms;
  float e = expf(acc - M);
  float sum = e;
  for (int o=1;o<64;o<<=1) sum += __shfl_xor(sum,o);
  __syncthreads();
  if (lane==0) red[wid]=sum;
  __syncthreads();
  if (c==0){ float t=0.f; for(int i=0;i<16;i++) t+=red[i]; Zs=t; }
  __syncthreads();
  start_lp[c] = acc - (M + logf(Zs));
}

// ---------------- transition head + row softmax -> P (bf16 probs) ----------------
#define RC 8
__global__ __launch_bounds__(256) void k_trans(
    const float* __restrict__ h2, const float* __restrict__ wo, const float* __restrict__ bo,
    u16* __restrict__ P){
  __shared__ float xr[RC][H];
  __shared__ float red[4];
  __shared__ float Ms, Zs;
  const int j = threadIdx.x, lane = j&63, wid = j>>6;
  const int r0 = blockIdx.x*RC;
  #pragma unroll
  for (int r=0;r<RC;r++) xr[r][j] = h2[(size_t)(r0+r)*H + j];
  __syncthreads();
  float acc[4][RC];
  #pragma unroll
  for (int m=0;m<4;m++){
    float bv = bo[j + 256*m];
    #pragma unroll
    for (int r=0;r<RC;r++) acc[m][r]=bv;
  }
  for (int k=0;k<H;k++){
    float w0 = wo[(size_t)k*C + j];
    float w1v = wo[(size_t)k*C + j + 256];
    float w2v = wo[(size_t)k*C + j + 512];
    float w3v = wo[(size_t)k*C + j + 768];
    #pragma unroll
    for (int r=0;r<RC;r++){
      float xv = xr[r][k];
      acc[0][r]=fmaf(xv,w0 ,acc[0][r]);
      acc[1][r]=fmaf(xv,w1v,acc[1][r]);
      acc[2][r]=fmaf(xv,w2v,acc[2][r]);
      acc[3][r]=fmaf(xv,w3v,acc[3][r]);
    }
  }
  for (int r=0;r<RC;r++){
    float mx = fmaxf(fmaxf(acc[0][r],acc[1][r]), fmaxf(acc[2][r],acc[3][r]));
    for (int o=1;o<64;o<<=1) mx = fmaxf(mx, __shfl_xor(mx,o));
    if (lane==0) red[wid]=mx;
    __syncthreads();
    if (j==0) Ms = fmaxf(fmaxf(red[0],red[1]),fmaxf(red[2],red[3]));
    __syncthreads();
    float M = Ms;
    float e0=expf(acc[0][r]-M), e1=expf(acc[1][r]-M), e2=expf(acc[2][r]-M), e3=expf(acc[3][r]-M);
    float sl = e0+e1+e2+e3;
    for (int o=1;o<64;o<<=1) sl += __shfl_xor(sl,o);
    __syncthreads();
    if (lane==0) red[wid]=sl;
    __syncthreads();
    if (j==0) Zs = red[0]+red[1]+red[2]+red[3];
    __syncthreads();
    float inv = 1.f/Zs;
    size_t base = (size_t)(r0+r)*C;
    P[base + j      ] = f2bf(e0*inv);
    P[base + j + 256] = f2bf(e1*inv);
    P[base + j + 512] = f2bf(e2*inv);
    P[base + j + 768] = f2bf(e3*inv);
    __syncthreads();
  }
}

// ---------------- transpose term_wo (H,V) -> wotb (VP,H) bf16, zero-padded ----------------
__global__ __launch_bounds__(256) void k_transpose(const float* __restrict__ wo, u16* __restrict__ wotb){
  __shared__ float tile[32][33];
  int v0 = blockIdx.x*32, k0 = blockIdx.y*32;
  int tx = threadIdx.x, ty = threadIdx.y; // 32 x 8
  for (int i=0;i<32;i+=8){
    int k = k0+ty+i, v = v0+tx;
    tile[ty+i][tx] = (v < V) ? wo[(size_t)k*V + v] : 0.f;
  }
  __syncthreads();
  for (int i=0;i<32;i+=8){
    int v = v0+ty+i, k = k0+tx;
    wotb[(size_t)v*H + k] = f2bf(tile[tx][ty+i]);
  }
}

// ---------------- max wotb row norm & max bias ----------------
__global__ __launch_bounds__(256) void k_wnorm(const u16* __restrict__ wotb, const float* __restrict__ bo,
                                               u32* __restrict__ wmax, u32* __restrict__ bmax){
  const int tid = threadIdx.x, lane = tid&63, wid = tid>>6;
  __shared__ float rn[4]; __shared__ float bb[4];
  int v = blockIdx.x*4 + wid;
  float s = 0.f;
  const u16* r = wotb + (size_t)v*H;
  for (int k=lane;k<H;k+=64){ float x=bf2f(r[k]); s = fmaf(x,x,s); }
  for (int o=1;o<64;o<<=1) s += __shfl_xor(s,o);
  if (lane==0) rn[wid] = sqrtf(s);
  int bi = blockIdx.x*256 + tid;
  float bv = (bi < V) ? bo[bi] : -1e30f;
  for (int o=1;o<64;o<<=1) bv = fmaxf(bv, __shfl_xor(bv,o));
  if (lane==0) bb[wid] = bv;
  __syncthreads();
  if (tid==0){
    float nm = fmaxf(fmaxf(rn[0],rn[1]),fmaxf(rn[2],rn[3]));
    float bm = fmaxf(fmaxf(bb[0],bb[1]),fmaxf(bb[2],bb[3]));
    atomicMax(wmax, fenc(nm));
    atomicMax(bmax, fenc(bm));
  }
}

__global__ void k_shift(const float* __restrict__ rn2, const u32* __restrict__ wb, float* __restrict__ shift){
  int c = threadIdx.x + blockIdx.x*blockDim.x;
  // 1.005 covers bf16 rounding of h (norms computed pre-rounding); +1.0 slack
  if (c < C) shift[c] = sqrtf(rn2[c]) * 1.005f * fdec(wb[0]) + fdec(wb[1]) + 1.0f;
}

// ---------------- EM = h2_term(C,H) @ wotb(VP,H)^T + bo  (bf16 MFMA, fp32 out) ----------------
__global__ __launch_bounds__(256) void k_em(
    const u16* __restrict__ A, const u16* __restrict__ BT,
    const float* __restrict__ bo, float* __restrict__ EM){
  __shared__ u16 As[128*LDK];
  __shared__ u16 Bs[128*LDK];
  const int tid = threadIdx.x;
  const int lane = tid & 63, wave = tid >> 6;
  const int wm = wave >> 1, wn = wave & 1;
  const int m0 = blockIdx.y * 128, n0 = blockIdx.x * 128;
  const int lr = lane & 15, lg = lane >> 4;
  f32x4 acc[4][4] = {};
  const int sr = tid >> 1, sh = (tid & 1) * 16;
  for (int ks = 0; ks < H; ks += 32){
    const u16* ga = A  + (size_t)(m0 + sr)*H + ks + sh;
    const u16* gb = BT + (size_t)(n0 + sr)*H + ks + sh;
    uint4 a0 = *(const uint4*)ga;
    uint4 a1 = *(const uint4*)(ga + 8);
    uint4 b0 = *(const uint4*)gb;
    uint4 b1 = *(const uint4*)(gb + 8);
    __syncthreads();
    *(uint4*)&As[sr*LDK + sh]     = a0;
    *(uint4*)&As[sr*LDK + sh + 8] = a1;
    *(uint4*)&Bs[sr*LDK + sh]     = b0;
    *(uint4*)&Bs[sr*LDK + sh + 8] = b1;
    __syncthreads();
    bf16x8 af[4], bfr[4];
    #pragma unroll
    for (int m=0;m<4;m++) af[m]  = *(const bf16x8*)&As[(wm*64 + m*16 + lr)*LDK + lg*8];
    #pragma unroll
    for (int n=0;n<4;n++) bfr[n] = *(const bf16x8*)&Bs[(wn*64 + n*16 + lr)*LDK + lg*8];
    #pragma unroll
    for (int m=0;m<4;m++)
      #pragma unroll
      for (int n=0;n<4;n++)
        acc[m][n] = __builtin_amdgcn_mfma_f32_16x16x32_bf16(af[m], bfr[n], acc[m][n], 0,0,0);
  }
  #pragma unroll
  for (int m=0;m<4;m++){
    int r_g = m0 + wm*64 + m*16 + lg*4;
    #pragma unroll
    for (int n=0;n<4;n++){
      int n_g = n0 + wn*64 + n*16 + lr;
      float bv = (n_g < V) ? bo[n_g] : 0.f;
      #pragma unroll
      for (int reg=0; reg<4; reg++){
        EM[(size_t)(r_g + reg)*VP + n_g] = acc[m][n][reg] + bv;
      }
    }
  }
}

// ---------------- gather LT + dedupe + masked LSE partial sums ----------------
__global__ __launch_bounds__(128) void k_gather(
    const int* __restrict__ w2s, const float* __restrict__ EM,
    const float* __restrict__ shift,
    float* __restrict__ LT, float* __restrict__ sumexp){
  const int v = blockIdx.x;
  const int s = threadIdx.x;
  __shared__ u32 bm[C/32];
  if (s < C/32) bm[s] = 0u;
  __syncthreads();
  const int c = w2s[(size_t)v*S + s];
  u32 old = atomicOr(&bm[c>>5], 1u<<(c&31));
  const bool first = ((old >> (c&31)) & 1u) == 0u;
  float val = EM[(size_t)c*VP + v];
  LT[(size_t)v*S + s] = val;
  if (first) atomicAdd(&sumexp[(size_t)(v & (NR-1))*C + c], expf(val - shift[c]));
}

__global__ void k_lse(const float* __restrict__ shift, const float* __restrict__ sumexp, float* __restrict__ lse){
  int c = threadIdx.x + blockIdx.x*blockDim.x;
  if (c < C){
    float s = 0.f;
    for (int r=0;r<NR;r++) s += sumexp[(size_t)r*C + c];
    lse[c] = shift[c] + logf(s);
  }
}

// ---------------- obs[b,t,s] = LT[text,s] - lse[c] ----------------
__global__ __launch_bounds__(128) void k_obs(
    const int* __restrict__ text, const int* __restrict__ w2s,
    const float* __restrict__ LT, const float* __restrict__ lse,
    float* __restrict__ obs){
  const int bt = blockIdx.x;
  const int s = threadIdx.x;
  const int v = text[bt];
  const int c = w2s[(size_t)v*S + s];
  obs[(size_t)bt*S + s] = LT[(size_t)v*S + s] - lse[c];
}

// ---------------- gather pot[b,t,sn,sp] = P[cp[sp], cn[sn]] * exp(obs[b,t+1,sn]) (bf16) ----------------
__global__ __launch_bounds__(256) void k_pot(
    const int* __restrict__ text, const int* __restrict__ w2s,
    const float* __restrict__ obs,
    const u16* __restrict__ P, u16* __restrict__ pot){
  const int t = blockIdx.x;  // 0..T-2
  const int b = blockIdx.y;
  __shared__ int cp[S], cn[S];
  __shared__ float eo[S];
  __shared__ u32 tileW[S*65];          // u16 tile [sn][sp], row stride 130 u16 (65 words)
  u16* tile16 = (u16*)tileW;
  const int tid = threadIdx.x;
  if (tid < 128){
    cp[tid] = w2s[(size_t)text[b*T + t  ]*S + tid];
    eo[tid] = expf(obs[((size_t)b*T + t + 1)*S + tid]);
  } else {
    cn[tid-128] = w2s[(size_t)text[b*T + t+1]*S + (tid-128)];
  }
  __syncthreads();
  const int sp_half = tid >> 7;
  const int sn = tid & 127;
  const int cnv = cn[sn];
  const float eov = eo[sn];
  for (int it=0; it<64; ++it){
    int sp = it*2 + sp_half;
    tile16[sn*130 + sp] = f2bf(bf2f(P[(size_t)cp[sp]*C + cnv]) * eov);
  }
  __syncthreads();
  u16* dst = pot + ((size_t)b*(T-1) + t)*S*S;
  #pragma unroll
  for (int ii=0; ii<(S*S)/(256*8); ++ii){
    int i0 = (ii*256 + tid)*8;
    int sn2 = i0>>7, sp2 = i0&127;
    const u32* tw = tileW + sn2*65 + (sp2>>1);
    uint4 w4; w4.x = tw[0]; w4.y = tw[1]; w4.z = tw[2]; w4.w = tw[3];
    *(uint4*)(dst + i0) = w4;
  }
}

// ---------------- sequential forward scan: pure linear space, sum-normalized ----------------
// u_{t+1} = M_{t+1} (u_t / Z_t),  Z_t = sum(u_t);  evidence = M0 + sum_t log Z_t
#define DOT8(cc, f0, f1) \
  acc0 = fmaf(__uint_as_float(cc##_0.x<<16),          f0.x, acc0); \
  acc1 = fmaf(__uint_as_float(cc##_0.x&0xFFFF0000u),  f0.y, acc1); \
  acc0 = fmaf(__uint_as_float(cc##_0.y<<16),          f0.z, acc0); \
  acc1 = fmaf(__uint_as_float(cc##_0.y&0xFFFF0000u),  f0.w, acc1); \
  acc0 = fmaf(__uint_as_float(cc##_0.z<<16),          f1.x, acc0); \
  acc1 = fmaf(__uint_as_float(cc##_0.z&0xFFFF0000u),  f1.y, acc1); \
  acc0 = fmaf(__uint_as_float(cc##_0.w<<16),          f1.z, acc0); \
  acc1 = fmaf(__uint_as_float(cc##_0.w&0xFFFF0000u),  f1.w, acc1);

#define LOADT(D, tt) { const u16* p_ = pb + (size_t)(tt)*(S*S); \
  D##0_0 = *(const uint4*)p_;      D##1_0 = *(const uint4*)(p_+8); \
  D##2_0 = *(const uint4*)(p_+16); D##3_0 = *(const uint4*)(p_+24); }

#define STEPM(CB, TT) { \
  float4 r0_ = *(const float4*)&red[cur][0]; \
  float4 r1_ = *(const float4*)&red[cur][4]; \
  float Z_ = ((r0_.x+r0_.y)+(r0_.z+r0_.w)) + ((r1_.x+r1_.y)+(r1_.z+r1_.w)); \
  float Zinv_ = 1.0f/Z_; \
  if (tid==0) zlog[TT] = Z_; \
  const float4* ap_ = (const float4*)&u[cur][q*36]; \
  float4 f0_=ap_[0], f1_=ap_[1], f2_=ap_[2], f3_=ap_[3]; \
  float4 f4_=ap_[4], f5_=ap_[5], f6_=ap_[6], f7_=ap_[7]; \
  float acc0=0.f, acc1=0.f; \
  DOT8(CB##0, f0_, f1_) DOT8(CB##1, f2_, f3_) DOT8(CB##2, f4_, f5_) DOT8(CB##3, f6_, f7_) \
  float acc_ = acc0+acc1; \
  acc_ += __shfl_xor(acc_,1); acc_ += __shfl_xor(acc_,2); \
  acc_ *= Zinv_; \
  if (q==0) u[cur^1][sn + ((sn>>5)<<2)] = acc_; \
  float ws_ = acc_; \
  ws_ += __shfl_xor(ws_,4); ws_ += __shfl_xor(ws_,8); ws_ += __shfl_xor(ws_,16); ws_ += __shfl_xor(ws_,32); \
  if (lane==0) red[cur^1][wid] = ws_; \
  __syncthreads(); \
  cur ^= 1; }

__global__ __launch_bounds__(512) void k_scan(
    const int* __restrict__ text, const int* __restrict__ w2s,
    const float* __restrict__ start_lp, const float* __restrict__ obs,
    const u16* __restrict__ pot, float* __restrict__ res){
  const int b = blockIdx.x;
  const int tid = threadIdx.x, lane = tid&63, wid = tid>>6;
  __shared__ float u[2][140];       // padded: index sp + (sp>>5)*4
  __shared__ float red[2][8];
  __shared__ float redm[8];
  __shared__ float zlog[128];
  float M0 = 0.f, val = 0.f;
  // ---- init: u_0 = exp(start_lp + obs_0 - M0) ----
  if (tid < 128){
    int c = w2s[(size_t)text[b*T]*S + tid];
    val = start_lp[c] + obs[(size_t)(b*T)*S + tid];
    float m = val;
    for (int o=1;o<64;o<<=1) m = fmaxf(m, __shfl_xor(m,o));
    if (lane==0) redm[wid] = m;
  }
  if (tid >= 130 && tid < 136) red[0][tid-128] = 0.f;
  __syncthreads();
  if (tid < 128){
    M0 = fmaxf(redm[0], redm[1]);
    float uv = expf(val - M0);
    u[0][tid + ((tid>>5)<<2)] = uv;
    float s = uv;
    for (int o=1;o<64;o<<=1) s += __shfl_xor(s,o);
    if (lane==0) red[0][wid] = s;
  }
  __syncthreads();

  const int sn = tid >> 2, q = tid & 3;
  const u16* pb = pot + (size_t)b*(T-1)*S*S + sn*S + q*32;
  uint4 A0_0,A1_0,A2_0,A3_0, B0_0,B1_0,B2_0,B3_0, C0_0,C1_0,C2_0,C3_0;
  LOADT(A, 0)
  LOADT(B, 1)
  int cur = 0;
  int t = 0;
  for (int it=0; it<42; ++it){
    LOADT(C, t+2)                      STEPM(A, t) t++;
    LOADT(A, t+2)                      STEPM(B, t) t++;
    { int nt = t+2; if (nt>126) nt=126; LOADT(B, nt) } STEPM(C, t) t++;
  }
  STEPM(A, 126)
  // ---- final Z ----
  {
    float4 r0_ = *(const float4*)&red[cur][0];
    float4 r1_ = *(const float4*)&red[cur][4];
    float Z_ = ((r0_.x+r0_.y)+(r0_.z+r0_.w)) + ((r1_.x+r1_.y)+(r1_.z+r1_.w));
    if (tid==0) zlog[127] = Z_;
  }
  __syncthreads();
  float lsum = 0.f;
  if (tid < 128){
    lsum = logf(zlog[tid]);
    for (int o=1;o<64;o<<=1) lsum += __shfl_xor(lsum,o);
    if (lane==0) redm[wid] = lsum;
  }
  __syncthreads();
  if (tid==0) res[b] = M0 + redm[0] + redm[1];
}

__global__ void k_final(const float* __restrict__ res, float* __restrict__ out){
  if (threadIdx.x==0){
    float s = 0.f;
    for (int i=0;i<B;i++) s += res[i];
    out[0] = s;
  }
}

extern "C" void kernel_launch(void* const* d_in, const int* in_sizes, int n_in,
                              void* d_out, int out_size, void* d_ws, size_t ws_size,
                              hipStream_t stream){
  const int*   text      = (const int*)d_in[0];
  const int*   w2s       = (const int*)d_in[1];
  const float* start_emb = (const float*)d_in[2];
  const float* start_w1  = (const float*)d_in[3];
  const float* start_b1  = (const float*)d_in[4];
  const float* start_w2  = (const float*)d_in[5];
  const float* start_b2  = (const float*)d_in[6];
  const float* start_wo  = (const float*)d_in[7];
  const float* start_bo  = (const float*)d_in[8];
  const float* state_emb = (const float*)d_in[9];
  const float* trans_w1  = (const float*)d_in[10];
  const float* trans_b1  = (const float*)d_in[11];
  const float* trans_w2  = (const float*)d_in[12];
  const float* trans_b2  = (const float*)d_in[13];
  const float* trans_wo  = (const float*)d_in[14];
  const float* trans_bo  = (const float*)d_in[15];
  const float* pre_emb   = (const float*)d_in[16];
  const float* term_w1   = (const float*)d_in[17];
  const float* term_b1   = (const float*)d_in[18];
  const float* term_w2   = (const float*)d_in[19];
  const float* term_b2   = (const float*)d_in[20];
  const float* term_wo   = (const float*)d_in[21];
  const float* term_bo   = (const float*)d_in[22];

  char* ws = (char*)d_ws;
  size_t off = 0;
  auto alloc = [&](size_t bytes)->char*{ char* p = ws + off; off += (bytes + 255) & ~(size_t)255; return p; };
  float* h2_start = (float*)alloc(sizeof(float)*(size_t)C*H);
  float* h2_trans = (float*)alloc(sizeof(float)*(size_t)C*H);
  u16*   h2_term  = (u16*)  alloc(sizeof(u16)*(size_t)C*H);
  float* rn2      = (float*)alloc(sizeof(float)*C);
  float* start_lp = (float*)alloc(sizeof(float)*C);
  float* shift    = (float*)alloc(sizeof(float)*C);
  float* sumexp   = (float*)alloc(sizeof(float)*(size_t)C*NR);
  float* lse      = (float*)alloc(sizeof(float)*C);
  u32*   wb       = (u32*)  alloc(sizeof(u32)*2);
  float* resb     = (float*)alloc(sizeof(float)*B);
  u16*   P        = (u16*)  alloc(sizeof(u16)*(size_t)C*C);
  u16*   wotb     = (u16*)  alloc(sizeof(u16)*(size_t)VP*H);
  float* LT       = (float*)alloc(sizeof(float)*(size_t)V*S);
  float* obs      = (float*)alloc(sizeof(float)*(size_t)B*T*S);
  u16*   pot      = (u16*)  alloc(sizeof(u16)*(size_t)B*(T-1)*S*S);  // >= EM bytes
  float* EM       = (float*)pot;   // aliased: EM dead before k_pot writes pot
  (void)ws_size; (void)in_sizes; (void)n_in; (void)out_size;

  k_zero<<<dim3((C*NR+255)/256), dim3(256), 0, stream>>>(sumexp, wb, resb);
  k_mlp<<<dim3(C/RPB), dim3(256), 0, stream>>>(start_emb, start_w1, start_b1, start_w2, start_b2, h2_start, (u16*)nullptr, (float*)nullptr);
  k_mlp<<<dim3(C/RPB), dim3(256), 0, stream>>>(state_emb, trans_w1, trans_b1, trans_w2, trans_b2, h2_trans, (u16*)nullptr, (float*)nullptr);
  k_mlp<<<dim3(C/RPB), dim3(256), 0, stream>>>(pre_emb, term_w1, term_b1, term_w2, term_b2, (float*)nullptr, h2_term, rn2);
  k_start<<<dim3(1), dim3(1024), 0, stream>>>(h2_start, start_wo, start_bo, start_lp);
  k_trans<<<dim3(C/RC), dim3(256), 0, stream>>>(h2_trans, trans_wo, trans_bo, P);
  k_transpose<<<dim3(VP/32, H/32), dim3(32,8), 0, stream>>>(term_wo, wotb);
  k_wnorm<<<dim3(VP/4), dim3(256), 0, stream>>>(wotb, term_bo, wb, wb+1);
  k_shift<<<dim3((C+255)/256), dim3(256), 0, stream>>>(rn2, wb, shift);
  k_em<<<dim3(VP/128, C/128), dim3(256), 0, stream>>>(h2_term, wotb, term_bo, EM);
  k_gather<<<dim3(V), dim3(128), 0, stream>>>(w2s, EM, shift, LT, sumexp);
  k_lse<<<dim3((C+255)/256), dim3(256), 0, stream>>>(shift, sumexp, lse);
  k_obs<<<dim3(B*T), dim3(128), 0, stream>>>(text, w2s, LT, lse, obs);
  k_pot<<<dim3(T-1, B), dim3(256), 0, stream>>>(text, w2s, obs, P, pot);
  k_scan<<<dim3(B), dim3(512), 0, stream>>>(text, w2s, start_lp, obs, pot, resb);
  k_final<<<dim3(1), dim3(64), 0, stream>>>(resb, (float*)d_out);
}